// Round 8
// baseline (469.400 us; speedup 1.0000x reference)
//
#include <hip/hip_runtime.h>
#include <math.h>

#define N_NODES 50000
#define N_EDGES 800000
#define SCAN_BLK 2048   // elements per scan block (256 threads x 8)
#define LDS_STRIDE 264  // 256 shorts + 8 pad (bank spread)

using short8  = __attribute__((ext_vector_type(8))) short;
using floatx4 = __attribute__((ext_vector_type(4))) float;
using ushortx8 = __attribute__((ext_vector_type(8))) unsigned short;
using uintx4  = __attribute__((ext_vector_type(4))) unsigned;
using uintx2  = __attribute__((ext_vector_type(2))) unsigned;

__device__ inline unsigned short f2bf(float f) {
  unsigned u = __float_as_uint(f);
  u += 0x7fff + ((u >> 16) & 1);   // round-to-nearest-even
  return (unsigned short)(u >> 16);
}

__device__ inline float sigmoidf(float x) { return 1.0f / (1.0f + __expf(-x)); }

// ---------------- prep: edge count || weight pack || x pack ----------------
__global__ void prep_kernel(const int* __restrict__ rows, int* __restrict__ counts, int E, int cntB,
                            const float* __restrict__ W1, const float* __restrict__ G1,
                            const float* __restrict__ W2, const float* __restrict__ G2,
                            unsigned short* __restrict__ Wp1, unsigned short* __restrict__ Gp1,
                            unsigned short* __restrict__ Wp2, unsigned short* __restrict__ Gp2,
                            const float* __restrict__ x, unsigned short* __restrict__ xp) {
  int b = blockIdx.x;
  if (b < cntB) {
    int e = b * 256 + threadIdx.x;
    if (e < E) atomicAdd(&counts[rows[e]], 1);
  } else if (b < cntB + 768) {
    int idx = (b - cntB) * 256 + threadIdx.x;
    if (idx < 65536) {
      int m = idx >> 8, k = idx & 255;
      Wp1[idx] = f2bf(W1[k * 256 + m]);
    } else if (idx < 131072) {
      int t = idx - 65536; int m = t >> 8, k = t & 255;
      Gp1[t] = f2bf(G1[k * 256 + m]);
    } else if (idx < 163840) {
      int t = idx - 131072; int m = t >> 8, k = t & 255;
      Wp2[t] = f2bf(W2[k * 128 + m]);
    } else {
      int t = idx - 163840; int m = t >> 8, k = t & 255;
      Gp2[t] = f2bf(G2[k * 128 + m]);
    }
  } else {
    int idx = (b - cntB - 768) * 256 + threadIdx.x;   // exactly N*256/8 threads
    size_t base = (size_t)idx * 8;
    floatx4 f0 = *(const floatx4*)(x + base);
    floatx4 f1 = *(const floatx4*)(x + base + 4);
    short8 o;
#pragma unroll
    for (int j = 0; j < 4; ++j) { o[j] = (short)f2bf(f0[j]); o[4 + j] = (short)f2bf(f1[j]); }
    *(short8*)(xp + base) = o;
  }
}

// ---------------- single-kernel exclusive scan ----------------
__global__ void scan_kernel(const int* __restrict__ counts, int* __restrict__ row_ptr,
                            int* __restrict__ cursor, int N, int E) {
  int tid = threadIdx.x, lane = tid & 63, wv = tid >> 6;
  __shared__ int wpart[4], wsum[4];

  int limit4 = (blockIdx.x * SCAN_BLK) >> 2;
  const int4* c4 = (const int4*)counts;
  int s = 0;
  for (int i = tid; i < limit4; i += 256) {
    int4 v = c4[i];
    s += v.x + v.y + v.z + v.w;
  }
#pragma unroll
  for (int d = 32; d > 0; d >>= 1) s += __shfl_down(s, d, 64);
  if (lane == 0) wpart[wv] = s;
  __syncthreads();
  int blk_off = wpart[0] + wpart[1] + wpart[2] + wpart[3];

  if (blockIdx.x == 0 && tid == 0) row_ptr[N] = E;

  int base = blockIdx.x * SCAN_BLK + tid * 8;
  int v[8];
  int sl = 0;
  if (base < N) {
#pragma unroll
    for (int j = 0; j < 8; ++j) { v[j] = counts[base + j]; sl += v[j]; }
  } else {
#pragma unroll
    for (int j = 0; j < 8; ++j) v[j] = 0;
  }
  int x = sl;
#pragma unroll
  for (int d = 1; d < 64; d <<= 1) {
    int y = __shfl_up(x, d, 64);
    if (lane >= d) x += y;
  }
  if (lane == 63) wsum[wv] = x;
  __syncthreads();
  int woff = 0;
  for (int w = 0; w < wv; ++w) woff += wsum[w];
  int run = blk_off + woff + (x - sl);
  if (base < N) {
#pragma unroll
    for (int j = 0; j < 8; ++j) {
      row_ptr[base + j] = run;
      cursor[base + j] = run;
      run += v[j];
    }
  }
}

// ---------------- scatter: edges into packed 8B {col,val} CSR records ----------------
__global__ __launch_bounds__(256) void scatter_kernel(const int* __restrict__ rows,
                                                      const int* __restrict__ cols,
                                                      const float* __restrict__ vals,
                                                      int* __restrict__ cursor,
                                                      uintx2* __restrict__ colval, int E) {
  int e = blockIdx.x * 256 + threadIdx.x;
  if (e >= E) return;
  int r = rows[e];
  int p = atomicAdd(&cursor[r], 1);
  uintx2 cv;
  cv[0] = (unsigned)cols[e];
  cv[1] = __float_as_uint(vals[e]);
  colval[p] = cv;
}

// ---------------- phase A core: row-per-half-wave gather, NON-TEMPORAL row loads ----------------
// Round-8 experiment: the row-gather loads carry the `nt` (non-temporal) flag, bypassing/
// deprioritizing L1 allocation. Rationale: per-CU L1 reuse for gathers is ~0 (each CU touches
// ~3000 distinct 512B rows vs 32KB L1), so L1 allocation is pure overhead; if the measured
// ~5.5 random-segments/ns device-wide wall is a per-CU L1/TCP allocation-tracking cap, nt
// reroutes requests to the deeper L2-side queues. colval loads stay cached (sequential,
// L1-friendly). Everything else identical to round 7 (single-variable A/B).
__device__ __forceinline__ void gather_row(const uintx2* __restrict__ colval,
                                           const unsigned short* __restrict__ src,
                                           int e0, int e1, int li, float a[8]) {
#pragma unroll
  for (int q = 0; q < 8; ++q) a[q] = 0.f;
  int n = e1 - e0;
  const uintx2* cv = colval + e0;
  int e = 0;
  for (; e + 4 <= n; e += 4) {
    uintx4 c01 = *(const uintx4*)(cv + e);       // records e, e+1
    uintx4 c23 = *(const uintx4*)(cv + e + 2);   // records e+2, e+3
    uintx4 p0 = __builtin_nontemporal_load(((const uintx4*)(src + (size_t)c01[0] * 256)) + li);
    uintx4 p1 = __builtin_nontemporal_load(((const uintx4*)(src + (size_t)c01[2] * 256)) + li);
    uintx4 p2 = __builtin_nontemporal_load(((const uintx4*)(src + (size_t)c23[0] * 256)) + li);
    uintx4 p3 = __builtin_nontemporal_load(((const uintx4*)(src + (size_t)c23[2] * 256)) + li);
    float v0 = __uint_as_float(c01[1]), v1 = __uint_as_float(c01[3]);
    float v2 = __uint_as_float(c23[1]), v3 = __uint_as_float(c23[3]);
#pragma unroll
    for (int q = 0; q < 4; ++q) {
      a[2 * q]     += __uint_as_float(p0[q] << 16) * v0;
      a[2 * q + 1] += __uint_as_float(p0[q] & 0xffff0000u) * v0;
    }
#pragma unroll
    for (int q = 0; q < 4; ++q) {
      a[2 * q]     += __uint_as_float(p1[q] << 16) * v1;
      a[2 * q + 1] += __uint_as_float(p1[q] & 0xffff0000u) * v1;
    }
#pragma unroll
    for (int q = 0; q < 4; ++q) {
      a[2 * q]     += __uint_as_float(p2[q] << 16) * v2;
      a[2 * q + 1] += __uint_as_float(p2[q] & 0xffff0000u) * v2;
    }
#pragma unroll
    for (int q = 0; q < 4; ++q) {
      a[2 * q]     += __uint_as_float(p3[q] << 16) * v3;
      a[2 * q + 1] += __uint_as_float(p3[q] & 0xffff0000u) * v3;
    }
  }
  for (; e < n; ++e) {
    uintx2 c = cv[e];
    uintx4 p = __builtin_nontemporal_load(((const uintx4*)(src + (size_t)c[0] * 256)) + li);
    float v = __uint_as_float(c[1]);
#pragma unroll
    for (int q = 0; q < 4; ++q) {
      a[2 * q]     += __uint_as_float(p[q] << 16) * v;
      a[2 * q + 1] += __uint_as_float(p[q] & 0xffff0000u) * v;
    }
  }
}

// ---------------- fused1: (A @ x) @ {W1,G1}, relu(sig*S) -> hp bf16 [N][256] ----------------
__global__ __launch_bounds__(512) void fused1_kernel(const int* __restrict__ row_ptr,
                                                     const uintx2* __restrict__ colval,
                                                     const unsigned short* __restrict__ xp,
                                                     const unsigned short* __restrict__ Wp,
                                                     const unsigned short* __restrict__ Gp,
                                                     unsigned short* __restrict__ hp) {
  __shared__ short hlds[16 * LDS_STRIDE];
  int lane = threadIdx.x & 63;
  int wid = threadIdx.x >> 6;
  int half = lane >> 5, li = lane & 31;
  int r0 = blockIdx.x * 16;
  int lrow = wid * 2 + half;
  int r = r0 + lrow;

  // ---- phase A ----
  int e0 = row_ptr[r], e1 = row_ptr[r + 1];
  float a[8];
  gather_row(colval, xp, e0, e1, li, a);
  ushortx8 o;
#pragma unroll
  for (int q = 0; q < 8; ++q) o[q] = f2bf(a[q]);
  *(ushortx8*)(&hlds[lrow * LDS_STRIDE + li * 8]) = o;
  __syncthreads();

  // ---- phase B: 16x256 @ 256x256 dual GEMM, relu(sig*S) epilogue ----
  constexpr int K = 256;
  int quad = lane >> 4, lr = lane & 15;
  int t0 = wid * 2;
  const short* Wb[2];
  const short* Gb[2];
#pragma unroll
  for (int t = 0; t < 2; ++t) {
    size_t boff = (size_t)(t0 + t) * 16 * K + (size_t)lr * K + quad * 8;
    Wb[t] = (const short*)Wp + boff;
    Gb[t] = (const short*)Gp + boff;
  }
  const short* Abase = &hlds[lr * LDS_STRIDE + quad * 8];

  floatx4 zero = {0.f, 0.f, 0.f, 0.f};
  floatx4 accS[2] = {zero, zero}, accG[2] = {zero, zero};
#pragma unroll
  for (int kc = 0; kc < 8; ++kc) {
    short8 av = *(const short8*)(Abase + kc * 32);
#pragma unroll
    for (int t = 0; t < 2; ++t) {
      short8 bw = *(const short8*)(Wb[t] + kc * 32);
      short8 bg = *(const short8*)(Gb[t] + kc * 32);
      accS[t] = __builtin_amdgcn_mfma_f32_16x16x32_bf16(av, bw, accS[t], 0, 0, 0);
      accG[t] = __builtin_amdgcn_mfma_f32_16x16x32_bf16(av, bg, accG[t], 0, 0, 0);
    }
  }
#pragma unroll
  for (int t = 0; t < 2; ++t)
#pragma unroll
    for (int gg = 0; gg < 4; ++gg) {
      int row = r0 + quad * 4 + gg;
      float h = sigmoidf(accG[t][gg]) * accS[t][gg];
      h = fmaxf(h, 0.f);
      hp[(size_t)row * 256 + (t0 + t) * 16 + lr] = f2bf(h);
    }
}

// ---------------- fused2: (A @ h) @ {W2,G2}, sig*S -> out f32 [N][128] ----------------
__global__ __launch_bounds__(512) void fused2_kernel(const int* __restrict__ row_ptr,
                                                     const uintx2* __restrict__ colval,
                                                     const unsigned short* __restrict__ hp,
                                                     const unsigned short* __restrict__ Wp,
                                                     const unsigned short* __restrict__ Gp,
                                                     float* __restrict__ out) {
  __shared__ short hlds[16 * LDS_STRIDE];
  int lane = threadIdx.x & 63;
  int wid = threadIdx.x >> 6;
  int half = lane >> 5, li = lane & 31;
  int r0 = blockIdx.x * 16;
  int lrow = wid * 2 + half;
  int r = r0 + lrow;

  // ---- phase A ----
  int e0 = row_ptr[r], e1 = row_ptr[r + 1];
  float a[8];
  gather_row(colval, hp, e0, e1, li, a);
  ushortx8 o;
#pragma unroll
  for (int q = 0; q < 8; ++q) o[q] = f2bf(a[q]);
  *(ushortx8*)(&hlds[lrow * LDS_STRIDE + li * 8]) = o;
  __syncthreads();

  // ---- phase B: 16x256 @ 256x128 dual GEMM, sig(G)*S epilogue (f32 out) ----
  constexpr int K = 256;
  int quad = lane >> 4, lr = lane & 15;
  int t = wid;  // 8 waves x 1 tile = 128 cols
  const short* Wb = (const short*)Wp + (size_t)t * 16 * K + (size_t)lr * K + quad * 8;
  const short* Gb = (const short*)Gp + (size_t)t * 16 * K + (size_t)lr * K + quad * 8;
  const short* Abase = &hlds[lr * LDS_STRIDE + quad * 8];

  floatx4 zero = {0.f, 0.f, 0.f, 0.f};
  floatx4 accS = zero, accG = zero;
#pragma unroll
  for (int kc = 0; kc < 8; ++kc) {
    short8 av = *(const short8*)(Abase + kc * 32);
    short8 bw = *(const short8*)(Wb + kc * 32);
    short8 bg = *(const short8*)(Gb + kc * 32);
    accS = __builtin_amdgcn_mfma_f32_16x16x32_bf16(av, bw, accS, 0, 0, 0);
    accG = __builtin_amdgcn_mfma_f32_16x16x32_bf16(av, bg, accG, 0, 0, 0);
  }
#pragma unroll
  for (int gg = 0; gg < 4; ++gg) {
    int row = r0 + quad * 4 + gg;
    out[(size_t)row * 128 + t * 16 + lr] = sigmoidf(accG[gg]) * accS[gg];
  }
}

// ---------------- launch ----------------

extern "C" void kernel_launch(void* const* d_in, const int* in_sizes, int n_in,
                              void* d_out, int out_size, void* d_ws, size_t ws_size,
                              hipStream_t stream) {
  const float* x    = (const float*)d_in[0];
  const int*   rows = (const int*)d_in[1];
  const int*   cols = (const int*)d_in[2];
  const float* vals = (const float*)d_in[3];
  const float* W1   = (const float*)d_in[4];
  const float* G1   = (const float*)d_in[5];
  const float* W2   = (const float*)d_in[6];
  const float* G2   = (const float*)d_in[7];

  const int N = N_NODES, E = N_EDGES;
  char* ws = (char*)d_ws;
  size_t off = 0;
  auto alloc = [&](size_t bytes) -> char* {
    off = (off + 255) & ~(size_t)255;
    char* p = ws + off;
    off += bytes;
    return p;
  };
  int*   counts  = (int*)alloc((size_t)N * 4);
  int*   row_ptr = (int*)alloc((size_t)(N + 1) * 4);
  int*   cursor  = (int*)alloc((size_t)N * 4);
  uintx2* colval = (uintx2*)alloc((size_t)E * 8);
  unsigned short* Wp1 = (unsigned short*)alloc(256 * 256 * 2);
  unsigned short* Gp1 = (unsigned short*)alloc(256 * 256 * 2);
  unsigned short* Wp2 = (unsigned short*)alloc(256 * 128 * 2);
  unsigned short* Gp2 = (unsigned short*)alloc(256 * 128 * 2);
  unsigned short* xp  = (unsigned short*)alloc((size_t)N * 256 * 2);  // bf16 x
  unsigned short* hp  = (unsigned short*)alloc((size_t)N * 256 * 2);  // bf16 h

  (void)hipMemsetAsync(counts, 0, (size_t)N * 4, stream);

  int cntB = (E + 255) / 256;           // 3125
  int packB = (N * 256 / 8) / 256;      // 6250
  prep_kernel<<<cntB + 768 + packB, 256, 0, stream>>>(rows, counts, E, cntB,
                                                      W1, G1, W2, G2, Wp1, Gp1, Wp2, Gp2, x, xp);

  int scanB = (N + SCAN_BLK - 1) / SCAN_BLK;   // 25
  scan_kernel<<<scanB, 256, 0, stream>>>(counts, row_ptr, cursor, N, E);

  scatter_kernel<<<cntB, 256, 0, stream>>>(rows, cols, vals, cursor, colval, E);

  // layer 1: (A @ x) @ {W1,G1}, relu(sig*S) -> hp
  fused1_kernel<<<N / 16, 512, 0, stream>>>(row_ptr, colval, xp, Wp1, Gp1, hp);

  // layer 2: (A @ h) @ {W2,G2}, sig*S -> out
  fused2_kernel<<<N / 16, 512, 0, stream>>>(row_ptr, colval, hp, Wp2, Gp2, (float*)d_out);
}

// Round 9
// 464.946 us; speedup vs baseline: 1.0096x; 1.0096x over previous
//
#include <hip/hip_runtime.h>
#include <math.h>

#define N_NODES 50000
#define N_EDGES 800000
#define SCAN_BLK 2048   // elements per scan block (256 threads x 8)
#define LDS_STRIDE 264  // 256 shorts + 8 pad (bank spread)

using short8  = __attribute__((ext_vector_type(8))) short;
using floatx4 = __attribute__((ext_vector_type(4))) float;
using ushortx4 = __attribute__((ext_vector_type(4))) unsigned short;
using ushortx8 = __attribute__((ext_vector_type(8))) unsigned short;
using uintx4  = __attribute__((ext_vector_type(4))) unsigned;
using uintx2  = __attribute__((ext_vector_type(2))) unsigned;

__device__ inline unsigned short f2bf(float f) {
  unsigned u = __float_as_uint(f);
  u += 0x7fff + ((u >> 16) & 1);   // round-to-nearest-even
  return (unsigned short)(u >> 16);
}

__device__ inline float sigmoidf(float x) { return 1.0f / (1.0f + __expf(-x)); }

// ---------------- prep: edge count || weight pack ----------------
// (xpack removed: fused1 now gathers f32 x directly — 1KB segments cost the same as
// 512B by the measured segment law, so the 77MB pack pass was pure overhead.)
__global__ void prep_kernel(const int* __restrict__ rows, int* __restrict__ counts, int E, int cntB,
                            const float* __restrict__ W1, const float* __restrict__ G1,
                            const float* __restrict__ W2, const float* __restrict__ G2,
                            unsigned short* __restrict__ Wp1, unsigned short* __restrict__ Gp1,
                            unsigned short* __restrict__ Wp2, unsigned short* __restrict__ Gp2) {
  int b = blockIdx.x;
  if (b < cntB) {
    int e = b * 256 + threadIdx.x;
    if (e < E) atomicAdd(&counts[rows[e]], 1);
  } else {
    int idx = (b - cntB) * 256 + threadIdx.x;
    if (idx < 65536) {
      int m = idx >> 8, k = idx & 255;
      Wp1[idx] = f2bf(W1[k * 256 + m]);
    } else if (idx < 131072) {
      int t = idx - 65536; int m = t >> 8, k = t & 255;
      Gp1[t] = f2bf(G1[k * 256 + m]);
    } else if (idx < 163840) {
      int t = idx - 131072; int m = t >> 8, k = t & 255;
      Wp2[t] = f2bf(W2[k * 128 + m]);
    } else {
      int t = idx - 163840; int m = t >> 8, k = t & 255;
      Gp2[t] = f2bf(G2[k * 128 + m]);
    }
  }
}

// ---------------- single-kernel exclusive scan ----------------
__global__ void scan_kernel(const int* __restrict__ counts, int* __restrict__ row_ptr,
                            int* __restrict__ cursor, int N, int E) {
  int tid = threadIdx.x, lane = tid & 63, wv = tid >> 6;
  __shared__ int wpart[4], wsum[4];

  int limit4 = (blockIdx.x * SCAN_BLK) >> 2;
  const int4* c4 = (const int4*)counts;
  int s = 0;
  for (int i = tid; i < limit4; i += 256) {
    int4 v = c4[i];
    s += v.x + v.y + v.z + v.w;
  }
#pragma unroll
  for (int d = 32; d > 0; d >>= 1) s += __shfl_down(s, d, 64);
  if (lane == 0) wpart[wv] = s;
  __syncthreads();
  int blk_off = wpart[0] + wpart[1] + wpart[2] + wpart[3];

  if (blockIdx.x == 0 && tid == 0) row_ptr[N] = E;

  int base = blockIdx.x * SCAN_BLK + tid * 8;
  int v[8];
  int sl = 0;
  if (base < N) {
#pragma unroll
    for (int j = 0; j < 8; ++j) { v[j] = counts[base + j]; sl += v[j]; }
  } else {
#pragma unroll
    for (int j = 0; j < 8; ++j) v[j] = 0;
  }
  int x = sl;
#pragma unroll
  for (int d = 1; d < 64; d <<= 1) {
    int y = __shfl_up(x, d, 64);
    if (lane >= d) x += y;
  }
  if (lane == 63) wsum[wv] = x;
  __syncthreads();
  int woff = 0;
  for (int w = 0; w < wv; ++w) woff += wsum[w];
  int run = blk_off + woff + (x - sl);
  if (base < N) {
#pragma unroll
    for (int j = 0; j < 8; ++j) {
      row_ptr[base + j] = run;
      cursor[base + j] = run;
      run += v[j];
    }
  }
}

// ---------------- scatter: edges into packed 8B {col,val} CSR records ----------------
// 2 edges/thread with int2 loads (E is even).
__global__ __launch_bounds__(256) void scatter_kernel(const int* __restrict__ rows,
                                                      const int* __restrict__ cols,
                                                      const float* __restrict__ vals,
                                                      int* __restrict__ cursor,
                                                      uintx2* __restrict__ colval, int E) {
  int e = (blockIdx.x * 256 + threadIdx.x) * 2;
  if (e >= E) return;
  int2 r2 = *(const int2*)(rows + e);
  int2 c2 = *(const int2*)(cols + e);
  float2 v2 = *(const float2*)(vals + e);
  int p0 = atomicAdd(&cursor[r2.x], 1);
  int p1 = atomicAdd(&cursor[r2.y], 1);
  uintx2 cv0, cv1;
  cv0[0] = (unsigned)c2.x; cv0[1] = __float_as_uint(v2.x);
  cv1[0] = (unsigned)c2.y; cv1[1] = __float_as_uint(v2.y);
  colval[p0] = cv0;
  colval[p1] = cv1;
}

// ---------------- fused1: (A @ x) @ {W1,G1}, relu(sig*S) -> hp bf16 [N][256] ----------------
// Phase A gathers RAW f32 x rows full-wave (64 lanes x 16B = 1KB = exactly one row,
// one instruction, ONE segment per edge — r0's proven shape at 5.4 segs/ns). Each wave
// does 2 rows serially -> 16 rows/block. No xpack, no bf16 pre-round of x (better
// numerics). 4-deep named-register pipeline; vectorized colval (2 records / 16B load).
__global__ __launch_bounds__(512) void fused1_kernel(const int* __restrict__ row_ptr,
                                                     const uintx2* __restrict__ colval,
                                                     const float* __restrict__ x,
                                                     const unsigned short* __restrict__ Wp,
                                                     const unsigned short* __restrict__ Gp,
                                                     unsigned short* __restrict__ hp) {
  __shared__ short hlds[16 * LDS_STRIDE];
  int lane = threadIdx.x & 63;
  int wid = threadIdx.x >> 6;
  int r0 = blockIdx.x * 16;

  // ---- phase A: two full-wave f32 row gathers per wave ----
  for (int rl = 0; rl < 2; ++rl) {
    int lrow = wid * 2 + rl;
    int r = r0 + lrow;
    int e0 = row_ptr[r], e1 = row_ptr[r + 1];
    float a[4];
#pragma unroll
    for (int q = 0; q < 4; ++q) a[q] = 0.f;
    int n = e1 - e0;
    const uintx2* cv = colval + e0;
    int e = 0;
    for (; e + 4 <= n; e += 4) {
      uintx4 c01 = *(const uintx4*)(cv + e);       // records e, e+1
      uintx4 c23 = *(const uintx4*)(cv + e + 2);   // records e+2, e+3
      floatx4 p0 = ((const floatx4*)(x + (size_t)c01[0] * 256))[lane];
      floatx4 p1 = ((const floatx4*)(x + (size_t)c01[2] * 256))[lane];
      floatx4 p2 = ((const floatx4*)(x + (size_t)c23[0] * 256))[lane];
      floatx4 p3 = ((const floatx4*)(x + (size_t)c23[2] * 256))[lane];
      float v0 = __uint_as_float(c01[1]), v1 = __uint_as_float(c01[3]);
      float v2 = __uint_as_float(c23[1]), v3 = __uint_as_float(c23[3]);
#pragma unroll
      for (int q = 0; q < 4; ++q) a[q] += p0[q] * v0;
#pragma unroll
      for (int q = 0; q < 4; ++q) a[q] += p1[q] * v1;
#pragma unroll
      for (int q = 0; q < 4; ++q) a[q] += p2[q] * v2;
#pragma unroll
      for (int q = 0; q < 4; ++q) a[q] += p3[q] * v3;
    }
    for (; e < n; ++e) {
      uintx2 c = cv[e];
      floatx4 p = ((const floatx4*)(x + (size_t)c[0] * 256))[lane];
      float v = __uint_as_float(c[1]);
#pragma unroll
      for (int q = 0; q < 4; ++q) a[q] += p[q] * v;
    }
    ushortx4 o;
#pragma unroll
    for (int q = 0; q < 4; ++q) o[q] = f2bf(a[q]);
    *(ushortx4*)(&hlds[lrow * LDS_STRIDE + lane * 4]) = o;
  }
  __syncthreads();

  // ---- phase B: 16x256 @ 256x256 dual GEMM, relu(sig*S) epilogue ----
  constexpr int K = 256;
  int quad = lane >> 4, lr = lane & 15;
  int t0 = wid * 2;
  const short* Wb[2];
  const short* Gb[2];
#pragma unroll
  for (int t = 0; t < 2; ++t) {
    size_t boff = (size_t)(t0 + t) * 16 * K + (size_t)lr * K + quad * 8;
    Wb[t] = (const short*)Wp + boff;
    Gb[t] = (const short*)Gp + boff;
  }
  const short* Abase = &hlds[lr * LDS_STRIDE + quad * 8];

  floatx4 zero = {0.f, 0.f, 0.f, 0.f};
  floatx4 accS[2] = {zero, zero}, accG[2] = {zero, zero};
#pragma unroll
  for (int kc = 0; kc < 8; ++kc) {
    short8 av = *(const short8*)(Abase + kc * 32);
#pragma unroll
    for (int t = 0; t < 2; ++t) {
      short8 bw = *(const short8*)(Wb[t] + kc * 32);
      short8 bg = *(const short8*)(Gb[t] + kc * 32);
      accS[t] = __builtin_amdgcn_mfma_f32_16x16x32_bf16(av, bw, accS[t], 0, 0, 0);
      accG[t] = __builtin_amdgcn_mfma_f32_16x16x32_bf16(av, bg, accG[t], 0, 0, 0);
    }
  }
#pragma unroll
  for (int t = 0; t < 2; ++t)
#pragma unroll
    for (int gg = 0; gg < 4; ++gg) {
      int row = r0 + quad * 4 + gg;
      float h = sigmoidf(accG[t][gg]) * accS[t][gg];
      h = fmaxf(h, 0.f);
      hp[(size_t)row * 256 + (t0 + t) * 16 + lr] = f2bf(h);
    }
}

// ---------------- fused2: (A @ h) @ {W2,G2}, sig*S -> out f32 [N][128] ----------------
// (unchanged from round 7: half-wave 512B bf16 gather of hp — at the segment law rate)
__global__ __launch_bounds__(512) void fused2_kernel(const int* __restrict__ row_ptr,
                                                     const uintx2* __restrict__ colval,
                                                     const unsigned short* __restrict__ hp,
                                                     const unsigned short* __restrict__ Wp,
                                                     const unsigned short* __restrict__ Gp,
                                                     float* __restrict__ out) {
  __shared__ short hlds[16 * LDS_STRIDE];
  int lane = threadIdx.x & 63;
  int wid = threadIdx.x >> 6;
  int half = lane >> 5, li = lane & 31;
  int r0 = blockIdx.x * 16;
  int lrow = wid * 2 + half;
  int r = r0 + lrow;

  // ---- phase A ----
  int e0 = row_ptr[r], e1 = row_ptr[r + 1];
  float a[8];
#pragma unroll
  for (int q = 0; q < 8; ++q) a[q] = 0.f;
  {
    int n = e1 - e0;
    const uintx2* cv = colval + e0;
    int e = 0;
    for (; e + 4 <= n; e += 4) {
      uintx4 c01 = *(const uintx4*)(cv + e);
      uintx4 c23 = *(const uintx4*)(cv + e + 2);
      uintx4 p0 = ((const uintx4*)(hp + (size_t)c01[0] * 256))[li];
      uintx4 p1 = ((const uintx4*)(hp + (size_t)c01[2] * 256))[li];
      uintx4 p2 = ((const uintx4*)(hp + (size_t)c23[0] * 256))[li];
      uintx4 p3 = ((const uintx4*)(hp + (size_t)c23[2] * 256))[li];
      float v0 = __uint_as_float(c01[1]), v1 = __uint_as_float(c01[3]);
      float v2 = __uint_as_float(c23[1]), v3 = __uint_as_float(c23[3]);
#pragma unroll
      for (int q = 0; q < 4; ++q) {
        a[2 * q]     += __uint_as_float(p0[q] << 16) * v0;
        a[2 * q + 1] += __uint_as_float(p0[q] & 0xffff0000u) * v0;
      }
#pragma unroll
      for (int q = 0; q < 4; ++q) {
        a[2 * q]     += __uint_as_float(p1[q] << 16) * v1;
        a[2 * q + 1] += __uint_as_float(p1[q] & 0xffff0000u) * v1;
      }
#pragma unroll
      for (int q = 0; q < 4; ++q) {
        a[2 * q]     += __uint_as_float(p2[q] << 16) * v2;
        a[2 * q + 1] += __uint_as_float(p2[q] & 0xffff0000u) * v2;
      }
#pragma unroll
      for (int q = 0; q < 4; ++q) {
        a[2 * q]     += __uint_as_float(p3[q] << 16) * v3;
        a[2 * q + 1] += __uint_as_float(p3[q] & 0xffff0000u) * v3;
      }
    }
    for (; e < n; ++e) {
      uintx2 c = cv[e];
      uintx4 p = ((const uintx4*)(hp + (size_t)c[0] * 256))[li];
      float v = __uint_as_float(c[1]);
#pragma unroll
      for (int q = 0; q < 4; ++q) {
        a[2 * q]     += __uint_as_float(p[q] << 16) * v;
        a[2 * q + 1] += __uint_as_float(p[q] & 0xffff0000u) * v;
      }
    }
  }
  ushortx8 o;
#pragma unroll
  for (int q = 0; q < 8; ++q) o[q] = f2bf(a[q]);
  *(ushortx8*)(&hlds[lrow * LDS_STRIDE + li * 8]) = o;
  __syncthreads();

  // ---- phase B: 16x256 @ 256x128 dual GEMM, sig(G)*S epilogue (f32 out) ----
  constexpr int K = 256;
  int quad = lane >> 4, lr = lane & 15;
  int t = wid;  // 8 waves x 1 tile = 128 cols
  const short* Wb = (const short*)Wp + (size_t)t * 16 * K + (size_t)lr * K + quad * 8;
  const short* Gb = (const short*)Gp + (size_t)t * 16 * K + (size_t)lr * K + quad * 8;
  const short* Abase = &hlds[lr * LDS_STRIDE + quad * 8];

  floatx4 zero = {0.f, 0.f, 0.f, 0.f};
  floatx4 accS = zero, accG = zero;
#pragma unroll
  for (int kc = 0; kc < 8; ++kc) {
    short8 av = *(const short8*)(Abase + kc * 32);
    short8 bw = *(const short8*)(Wb + kc * 32);
    short8 bg = *(const short8*)(Gb + kc * 32);
    accS = __builtin_amdgcn_mfma_f32_16x16x32_bf16(av, bw, accS, 0, 0, 0);
    accG = __builtin_amdgcn_mfma_f32_16x16x32_bf16(av, bg, accG, 0, 0, 0);
  }
#pragma unroll
  for (int gg = 0; gg < 4; ++gg) {
    int row = r0 + quad * 4 + gg;
    out[(size_t)row * 128 + t * 16 + lr] = sigmoidf(accG[gg]) * accS[gg];
  }
}

// ---------------- launch ----------------

extern "C" void kernel_launch(void* const* d_in, const int* in_sizes, int n_in,
                              void* d_out, int out_size, void* d_ws, size_t ws_size,
                              hipStream_t stream) {
  const float* x    = (const float*)d_in[0];
  const int*   rows = (const int*)d_in[1];
  const int*   cols = (const int*)d_in[2];
  const float* vals = (const float*)d_in[3];
  const float* W1   = (const float*)d_in[4];
  const float* G1   = (const float*)d_in[5];
  const float* W2   = (const float*)d_in[6];
  const float* G2   = (const float*)d_in[7];

  const int N = N_NODES, E = N_EDGES;
  char* ws = (char*)d_ws;
  size_t off = 0;
  auto alloc = [&](size_t bytes) -> char* {
    off = (off + 255) & ~(size_t)255;
    char* p = ws + off;
    off += bytes;
    return p;
  };
  int*   counts  = (int*)alloc((size_t)N * 4);
  int*   row_ptr = (int*)alloc((size_t)(N + 1) * 4);
  int*   cursor  = (int*)alloc((size_t)N * 4);
  uintx2* colval = (uintx2*)alloc((size_t)E * 8);
  unsigned short* Wp1 = (unsigned short*)alloc(256 * 256 * 2);
  unsigned short* Gp1 = (unsigned short*)alloc(256 * 256 * 2);
  unsigned short* Wp2 = (unsigned short*)alloc(256 * 128 * 2);
  unsigned short* Gp2 = (unsigned short*)alloc(256 * 128 * 2);
  unsigned short* hp  = (unsigned short*)alloc((size_t)N * 256 * 2);  // bf16 h

  (void)hipMemsetAsync(counts, 0, (size_t)N * 4, stream);

  int cntB = (E + 255) / 256;           // 3125
  prep_kernel<<<cntB + 768, 256, 0, stream>>>(rows, counts, E, cntB,
                                              W1, G1, W2, G2, Wp1, Gp1, Wp2, Gp2);

  int scanB = (N + SCAN_BLK - 1) / SCAN_BLK;   // 25
  scan_kernel<<<scanB, 256, 0, stream>>>(counts, row_ptr, cursor, N, E);

  int sctB = (E / 2 + 255) / 256;       // 1563
  scatter_kernel<<<sctB, 256, 0, stream>>>(rows, cols, vals, cursor, colval, E);

  // layer 1: (A @ x) @ {W1,G1}, relu(sig*S) -> hp   (f32 x gathered directly)
  fused1_kernel<<<N / 16, 512, 0, stream>>>(row_ptr, colval, x, Wp1, Gp1, hp);

  // layer 2: (A @ h) @ {W2,G2}, sig*S -> out
  fused2_kernel<<<N / 16, 512, 0, stream>>>(row_ptr, colval, hp, Wp2, Gp2, (float*)d_out);
}

// Round 10
// 384.917 us; speedup vs baseline: 1.2195x; 1.2079x over previous
//
#include <hip/hip_runtime.h>
#include <math.h>

#define N_NODES 50000
#define N_EDGES 800000
#define CAP 64            // bucket capacity per row (Poisson(16): P(deg>64) ~ 1e-18/row)
#define OVF_MAX 100000    // overflow list capacity (exact-fallback; expected use: 0)
#define LDS_STRIDE 264    // 256 shorts + 8 pad (bank spread)

using short8  = __attribute__((ext_vector_type(8))) short;
using floatx4 = __attribute__((ext_vector_type(4))) float;
using ushortx8 = __attribute__((ext_vector_type(8))) unsigned short;
using uintx4  = __attribute__((ext_vector_type(4))) unsigned;
using uintx2  = __attribute__((ext_vector_type(2))) unsigned;

__device__ inline unsigned short f2bf(float f) {
  unsigned u = __float_as_uint(f);
  u += 0x7fff + ((u >> 16) & 1);   // round-to-nearest-even
  return (unsigned short)(u >> 16);
}

__device__ inline float sigmoidf(float x) { return 1.0f / (1.0f + __expf(-x)); }

// ---------------- mega-prep: bucket scatter || weight pack || x pack ----------------
// Fixed-capacity bucket CSR kills the count pass AND the scan: scatter needs only
// zeroed cursors. The atomic/latency-bound scatter co-runs with the BW-bound xpack
// and the tiny wpack in one launch. Overflow (P~0, but handled EXACTLY): edges beyond
// CAP go to a side list scanned by the fused kernels' rare path.
__global__ __launch_bounds__(256) void prep_kernel(const int* __restrict__ rows,
                                                   const int* __restrict__ cols,
                                                   const float* __restrict__ vals,
                                                   int* __restrict__ cursor,
                                                   uintx2* __restrict__ colval,
                                                   int4* __restrict__ ovf, int* __restrict__ ovf_cnt,
                                                   int E, int sctB,
                                                   const float* __restrict__ W1, const float* __restrict__ G1,
                                                   const float* __restrict__ W2, const float* __restrict__ G2,
                                                   unsigned short* __restrict__ Wp1, unsigned short* __restrict__ Gp1,
                                                   unsigned short* __restrict__ Wp2, unsigned short* __restrict__ Gp2,
                                                   const float* __restrict__ x, unsigned short* __restrict__ xp) {
  int b = blockIdx.x;
  if (b < sctB) {
    int e = (b * 256 + threadIdx.x) * 2;
    if (e >= E) return;
    int2 r2 = *(const int2*)(rows + e);
    int2 c2 = *(const int2*)(cols + e);
    float2 v2 = *(const float2*)(vals + e);
    int p0 = atomicAdd(&cursor[r2.x], 1);
    if (p0 < CAP) {
      uintx2 cv; cv[0] = (unsigned)c2.x; cv[1] = __float_as_uint(v2.x);
      colval[((size_t)r2.x << 6) + p0] = cv;
    } else {
      int o = atomicAdd(ovf_cnt, 1);
      if (o < OVF_MAX) ovf[o] = make_int4(r2.x, c2.x, __float_as_int(v2.x), 0);
    }
    int p1 = atomicAdd(&cursor[r2.y], 1);
    if (p1 < CAP) {
      uintx2 cv; cv[0] = (unsigned)c2.y; cv[1] = __float_as_uint(v2.y);
      colval[((size_t)r2.y << 6) + p1] = cv;
    } else {
      int o = atomicAdd(ovf_cnt, 1);
      if (o < OVF_MAX) ovf[o] = make_int4(r2.y, c2.y, __float_as_int(v2.y), 0);
    }
  } else if (b < sctB + 768) {
    int idx = (b - sctB) * 256 + threadIdx.x;
    if (idx < 65536) {
      int m = idx >> 8, k = idx & 255;
      Wp1[idx] = f2bf(W1[k * 256 + m]);
    } else if (idx < 131072) {
      int t = idx - 65536; int m = t >> 8, k = t & 255;
      Gp1[t] = f2bf(G1[k * 256 + m]);
    } else if (idx < 163840) {
      int t = idx - 131072; int m = t >> 8, k = t & 255;
      Wp2[t] = f2bf(W2[k * 128 + m]);
    } else {
      int t = idx - 163840; int m = t >> 8, k = t & 255;
      Gp2[t] = f2bf(G2[k * 128 + m]);
    }
  } else {
    int idx = (b - sctB - 768) * 256 + threadIdx.x;   // exactly N*256/8 threads
    size_t base = (size_t)idx * 8;
    floatx4 f0 = *(const floatx4*)(x + base);
    floatx4 f1 = *(const floatx4*)(x + base + 4);
    short8 o;
#pragma unroll
    for (int j = 0; j < 4; ++j) { o[j] = (short)f2bf(f0[j]); o[4 + j] = (short)f2bf(f1[j]); }
    *(short8*)(xp + base) = o;
  }
}

// ---------------- phase A core: row-per-half-wave bucket gather (r7-proven shape) ----------------
__device__ __forceinline__ void gather_row(const uintx2* __restrict__ cv,
                                           const unsigned short* __restrict__ src,
                                           int n, int li, float a[8]) {
#pragma unroll
  for (int q = 0; q < 8; ++q) a[q] = 0.f;
  int e = 0;
  for (; e + 4 <= n; e += 4) {
    uintx4 c01 = *(const uintx4*)(cv + e);       // records e, e+1
    uintx4 c23 = *(const uintx4*)(cv + e + 2);   // records e+2, e+3
    uintx4 p0 = ((const uintx4*)(src + (size_t)c01[0] * 256))[li];
    uintx4 p1 = ((const uintx4*)(src + (size_t)c01[2] * 256))[li];
    uintx4 p2 = ((const uintx4*)(src + (size_t)c23[0] * 256))[li];
    uintx4 p3 = ((const uintx4*)(src + (size_t)c23[2] * 256))[li];
    float v0 = __uint_as_float(c01[1]), v1 = __uint_as_float(c01[3]);
    float v2 = __uint_as_float(c23[1]), v3 = __uint_as_float(c23[3]);
#pragma unroll
    for (int q = 0; q < 4; ++q) {
      a[2 * q]     += __uint_as_float(p0[q] << 16) * v0;
      a[2 * q + 1] += __uint_as_float(p0[q] & 0xffff0000u) * v0;
    }
#pragma unroll
    for (int q = 0; q < 4; ++q) {
      a[2 * q]     += __uint_as_float(p1[q] << 16) * v1;
      a[2 * q + 1] += __uint_as_float(p1[q] & 0xffff0000u) * v1;
    }
#pragma unroll
    for (int q = 0; q < 4; ++q) {
      a[2 * q]     += __uint_as_float(p2[q] << 16) * v2;
      a[2 * q + 1] += __uint_as_float(p2[q] & 0xffff0000u) * v2;
    }
#pragma unroll
    for (int q = 0; q < 4; ++q) {
      a[2 * q]     += __uint_as_float(p3[q] << 16) * v3;
      a[2 * q + 1] += __uint_as_float(p3[q] & 0xffff0000u) * v3;
    }
  }
  for (; e < n; ++e) {
    uintx2 c = cv[e];
    uintx4 p = ((const uintx4*)(src + (size_t)c[0] * 256))[li];
    float v = __uint_as_float(c[1]);
#pragma unroll
    for (int q = 0; q < 4; ++q) {
      a[2 * q]     += __uint_as_float(p[q] << 16) * v;
      a[2 * q + 1] += __uint_as_float(p[q] & 0xffff0000u) * v;
    }
  }
}

// exact rare-path: fold any overflow edges for row r into the accumulator
__device__ __forceinline__ void gather_ovf(const int4* __restrict__ ovf, int on, int r,
                                           const unsigned short* __restrict__ src,
                                           int li, float a[8]) {
  for (int i = 0; i < on; ++i) {
    int4 oe = ovf[i];
    if (oe.x == r) {
      uintx4 p = ((const uintx4*)(src + (size_t)oe.y * 256))[li];
      float v = __int_as_float(oe.z);
#pragma unroll
      for (int q = 0; q < 4; ++q) {
        a[2 * q]     += __uint_as_float(p[q] << 16) * v;
        a[2 * q + 1] += __uint_as_float(p[q] & 0xffff0000u) * v;
      }
    }
  }
}

// ---------------- fused1: (A @ x) @ {W1,G1}, relu(sig*S) -> hp bf16 [N][256] ----------------
__global__ __launch_bounds__(512) void fused1_kernel(const int* __restrict__ cursor,
                                                     const uintx2* __restrict__ colval,
                                                     const int4* __restrict__ ovf,
                                                     const int* __restrict__ ovf_cnt,
                                                     const unsigned short* __restrict__ xp,
                                                     const unsigned short* __restrict__ Wp,
                                                     const unsigned short* __restrict__ Gp,
                                                     unsigned short* __restrict__ hp) {
  __shared__ short hlds[16 * LDS_STRIDE];
  int lane = threadIdx.x & 63;
  int wid = threadIdx.x >> 6;
  int half = lane >> 5, li = lane & 31;
  int r0 = blockIdx.x * 16;
  int lrow = wid * 2 + half;
  int r = r0 + lrow;

  // ---- phase A ----
  int deg = cursor[r];
  int n = deg < CAP ? deg : CAP;
  float a[8];
  gather_row(colval + ((size_t)r << 6), xp, n, li, a);
  int on = *ovf_cnt;
  if (on > 0) gather_ovf(ovf, on, r, xp, li, a);
  ushortx8 o;
#pragma unroll
  for (int q = 0; q < 8; ++q) o[q] = f2bf(a[q]);
  *(ushortx8*)(&hlds[lrow * LDS_STRIDE + li * 8]) = o;
  __syncthreads();

  // ---- phase B: 16x256 @ 256x256 dual GEMM, relu(sig*S) epilogue ----
  constexpr int K = 256;
  int quad = lane >> 4, lr = lane & 15;
  int t0 = wid * 2;
  const short* Wb[2];
  const short* Gb[2];
#pragma unroll
  for (int t = 0; t < 2; ++t) {
    size_t boff = (size_t)(t0 + t) * 16 * K + (size_t)lr * K + quad * 8;
    Wb[t] = (const short*)Wp + boff;
    Gb[t] = (const short*)Gp + boff;
  }
  const short* Abase = &hlds[lr * LDS_STRIDE + quad * 8];

  floatx4 zero = {0.f, 0.f, 0.f, 0.f};
  floatx4 accS[2] = {zero, zero}, accG[2] = {zero, zero};
#pragma unroll
  for (int kc = 0; kc < 8; ++kc) {
    short8 av = *(const short8*)(Abase + kc * 32);
#pragma unroll
    for (int t = 0; t < 2; ++t) {
      short8 bw = *(const short8*)(Wb[t] + kc * 32);
      short8 bg = *(const short8*)(Gb[t] + kc * 32);
      accS[t] = __builtin_amdgcn_mfma_f32_16x16x32_bf16(av, bw, accS[t], 0, 0, 0);
      accG[t] = __builtin_amdgcn_mfma_f32_16x16x32_bf16(av, bg, accG[t], 0, 0, 0);
    }
  }
#pragma unroll
  for (int t = 0; t < 2; ++t)
#pragma unroll
    for (int gg = 0; gg < 4; ++gg) {
      int row = r0 + quad * 4 + gg;
      float h = sigmoidf(accG[t][gg]) * accS[t][gg];
      h = fmaxf(h, 0.f);
      hp[(size_t)row * 256 + (t0 + t) * 16 + lr] = f2bf(h);
    }
}

// ---------------- fused2: (A @ h) @ {W2,G2}, sig*S -> out f32 [N][128] ----------------
__global__ __launch_bounds__(512) void fused2_kernel(const int* __restrict__ cursor,
                                                     const uintx2* __restrict__ colval,
                                                     const int4* __restrict__ ovf,
                                                     const int* __restrict__ ovf_cnt,
                                                     const unsigned short* __restrict__ hp,
                                                     const unsigned short* __restrict__ Wp,
                                                     const unsigned short* __restrict__ Gp,
                                                     float* __restrict__ out) {
  __shared__ short hlds[16 * LDS_STRIDE];
  int lane = threadIdx.x & 63;
  int wid = threadIdx.x >> 6;
  int half = lane >> 5, li = lane & 31;
  int r0 = blockIdx.x * 16;
  int lrow = wid * 2 + half;
  int r = r0 + lrow;

  // ---- phase A ----
  int deg = cursor[r];
  int n = deg < CAP ? deg : CAP;
  float a[8];
  gather_row(colval + ((size_t)r << 6), hp, n, li, a);
  int on = *ovf_cnt;
  if (on > 0) gather_ovf(ovf, on, r, hp, li, a);
  ushortx8 o;
#pragma unroll
  for (int q = 0; q < 8; ++q) o[q] = f2bf(a[q]);
  *(ushortx8*)(&hlds[lrow * LDS_STRIDE + li * 8]) = o;
  __syncthreads();

  // ---- phase B: 16x256 @ 256x128 dual GEMM, sig(G)*S epilogue (f32 out) ----
  constexpr int K = 256;
  int quad = lane >> 4, lr = lane & 15;
  int t = wid;  // 8 waves x 1 tile = 128 cols
  const short* Wb = (const short*)Wp + (size_t)t * 16 * K + (size_t)lr * K + quad * 8;
  const short* Gb = (const short*)Gp + (size_t)t * 16 * K + (size_t)lr * K + quad * 8;
  const short* Abase = &hlds[lr * LDS_STRIDE + quad * 8];

  floatx4 zero = {0.f, 0.f, 0.f, 0.f};
  floatx4 accS = zero, accG = zero;
#pragma unroll
  for (int kc = 0; kc < 8; ++kc) {
    short8 av = *(const short8*)(Abase + kc * 32);
    short8 bw = *(const short8*)(Wb + kc * 32);
    short8 bg = *(const short8*)(Gb + kc * 32);
    accS = __builtin_amdgcn_mfma_f32_16x16x32_bf16(av, bw, accS, 0, 0, 0);
    accG = __builtin_amdgcn_mfma_f32_16x16x32_bf16(av, bg, accG, 0, 0, 0);
  }
#pragma unroll
  for (int gg = 0; gg < 4; ++gg) {
    int row = r0 + quad * 4 + gg;
    out[(size_t)row * 128 + t * 16 + lr] = sigmoidf(accG[gg]) * accS[gg];
  }
}

// ---------------- launch ----------------

extern "C" void kernel_launch(void* const* d_in, const int* in_sizes, int n_in,
                              void* d_out, int out_size, void* d_ws, size_t ws_size,
                              hipStream_t stream) {
  const float* x    = (const float*)d_in[0];
  const int*   rows = (const int*)d_in[1];
  const int*   cols = (const int*)d_in[2];
  const float* vals = (const float*)d_in[3];
  const float* W1   = (const float*)d_in[4];
  const float* G1   = (const float*)d_in[5];
  const float* W2   = (const float*)d_in[6];
  const float* G2   = (const float*)d_in[7];

  const int N = N_NODES, E = N_EDGES;
  char* ws = (char*)d_ws;
  size_t off = 0;
  auto alloc = [&](size_t bytes) -> char* {
    off = (off + 255) & ~(size_t)255;
    char* p = ws + off;
    off += bytes;
    return p;
  };
  int*   cursor  = (int*)alloc((size_t)N * 4);          // per-row degree counters
  int*   ovf_cnt = (int*)alloc(256);                    // adjacent to cursor (one memset)
  int4*  ovf     = (int4*)alloc((size_t)OVF_MAX * 16);
  uintx2* colval = (uintx2*)alloc((size_t)N * CAP * 8); // bucketed CSR, 512B-aligned rows
  unsigned short* Wp1 = (unsigned short*)alloc(256 * 256 * 2);
  unsigned short* Gp1 = (unsigned short*)alloc(256 * 256 * 2);
  unsigned short* Wp2 = (unsigned short*)alloc(256 * 128 * 2);
  unsigned short* Gp2 = (unsigned short*)alloc(256 * 128 * 2);
  unsigned short* xp  = (unsigned short*)alloc((size_t)N * 256 * 2);  // bf16 x
  unsigned short* hp  = (unsigned short*)alloc((size_t)N * 256 * 2);  // bf16 h

  (void)hipMemsetAsync(cursor, 0, (size_t)N * 4 + 256, stream);   // cursor + ovf_cnt

  int sctB  = (E / 2 + 255) / 256;      // 1563
  int packB = (N * 256 / 8) / 256;      // 6250
  prep_kernel<<<sctB + 768 + packB, 256, 0, stream>>>(rows, cols, vals, cursor, colval,
                                                      ovf, ovf_cnt, E, sctB,
                                                      W1, G1, W2, G2, Wp1, Gp1, Wp2, Gp2, x, xp);

  // layer 1: (A @ x) @ {W1,G1}, relu(sig*S) -> hp
  fused1_kernel<<<N / 16, 512, 0, stream>>>(cursor, colval, ovf, ovf_cnt, xp, Wp1, Gp1, hp);

  // layer 2: (A @ h) @ {W2,G2}, sig*S -> out
  fused2_kernel<<<N / 16, 512, 0, stream>>>(cursor, colval, ovf, ovf_cnt, hp, Wp2, Gp2, (float*)d_out);
}